// Round 2
// baseline (50.719 us; speedup 1.0000x reference)
//
#include <hip/hip_runtime.h>
#include <math.h>

#define SEQ_LEN 4096
#define KSZ 128
#define OUT_LEN 3969
#define BATCH 8192
#define NB_MAX 1024

// One wave = one row. No barriers in the row loop.
// Per row: 16 independent float4 loads, pairwise sum, XOR-butterfly reduce
// (all lanes get identical totals), redundant sigmoid/dconv on all lanes,
// per-lane FMA into 4 edge-gradient accumulators held in registers.
// Head elems x[0..127] = lanes 0..31 of load 0; tail x[3968..4095] = lanes
// 32..63 of load 15. corr weight for j=127 is P[127]-ksum = 0 (interior).
__global__ __launch_bounds__(256, 4) void conv1d_train_main(
    const float* __restrict__ x, const float* __restrict__ y,
    const float* __restrict__ kern, const float* __restrict__ bias,
    float* __restrict__ partial, int nb)
{
    __shared__ float kk[KSZ];
    __shared__ float P[KSZ];      // inclusive prefix sums of kernel
    __shared__ float sl[4][256];  // per-wave partial layout for block combine

    const int tid  = threadIdx.x;
    const int wave = tid >> 6;
    const int lane = tid & 63;

    if (tid < KSZ) kk[tid] = kern[tid];
    __syncthreads();
    if (tid < KSZ) {
        float s = 0.f;
        for (int j = 0; j <= tid; ++j) s += kk[j];   // LDS broadcast reads
        P[tid] = s;
    }
    __syncthreads();
    const float ksum = P[KSZ - 1];
    const float bs   = bias[0];

    // Per-lane edge-correction weights.
    // head lane l<32: elems j=4l..4l+3, weight P[j]-ksum  (j=127 -> 0)
    // tail lane l>=32: elems 3968+4(l-32)+q, m=4(l-32)+q-1, weight -P[m]; m=-1 -> 0
    float w0, w1, w2, w3;
    if (lane < 32) {
        const int j = 4 * lane;
        w0 = P[j] - ksum; w1 = P[j + 1] - ksum;
        w2 = P[j + 2] - ksum; w3 = P[j + 3] - ksum;
    } else {
        const int m = 4 * (lane - 32) - 1;
        w0 = (m >= 0) ? -P[m] : 0.f;
        w1 = -P[m + 1]; w2 = -P[m + 2]; w3 = -P[m + 3];
    }

    float g0 = 0.f, g1 = 0.f, g2 = 0.f, g3 = 0.f;  // dconv-weighted edge accum
    float C0 = 0.f, db = 0.f;

    const int wg     = blockIdx.x * 4 + wave;
    const int stride = nb * 4;

    for (int b = wg; b < BATCH; b += stride) {
        const float4* xr = reinterpret_cast<const float4*>(x + (size_t)b * SEQ_LEN);
        float4 r[16];
#pragma unroll
        for (int i = 0; i < 16; ++i) r[i] = xr[i * 64 + lane];
        const float yv = y[b];                       // broadcast load

        float tot = 0.f;
#pragma unroll
        for (int i = 0; i < 16; ++i) tot += (r[i].x + r[i].y) + (r[i].z + r[i].w);

        const float4 e = (lane < 32) ? r[0] : r[15];
        float corr = ((w0 * e.x + w1 * e.y) + (w2 * e.z + w3 * e.w));

        float t = tot, c = corr;
#pragma unroll
        for (int off = 1; off < 64; off <<= 1) {
            t += __shfl_xor(t, off, 64);
            c += __shfl_xor(c, off, 64);
        }
        // all lanes now hold identical t, c
        const float logits = (ksum * t + c) * (1.f / (float)OUT_LEN) + bs;
        const float sig    = 1.f / (1.f + expf(-logits));
        const float dconv  = (sig - yv) * (1.f / (float)OUT_LEN);

        g0 += dconv * e.x; g1 += dconv * e.y;
        g2 += dconv * e.z; g3 += dconv * e.w;
        C0 += dconv * t;   db += dconv;
    }

    // Per-wave writeout to LDS: [0..126]=G, [127]=C0, [128..254]=H, [255]=db
    if (lane < 32) {
        const int j = 4 * lane;
        sl[wave][j]     = g0;
        sl[wave][j + 1] = g1;
        sl[wave][j + 2] = g2;
        if (j + 3 < 127) sl[wave][j + 3] = g3;   // skip unused G[127]
    } else {
        const int s0 = 4 * lane - 1;             // slot = 128 + m
        if (lane > 32) sl[wave][s0] = g0;        // lane 32 q=0 -> m=-1, skip
        sl[wave][s0 + 1] = g1;
        sl[wave][s0 + 2] = g2;
        sl[wave][s0 + 3] = g3;                   // lane 63 -> slot 254
    }
    if (lane == 0) { sl[wave][127] = C0; sl[wave][255] = db; }
    __syncthreads();
    if (tid < 256) {
        const float s = (sl[0][tid] + sl[1][tid]) + (sl[2][tid] + sl[3][tid]);
        partial[(size_t)blockIdx.x * 256 + tid] = s;
    }
}

// Final reduce: column-sum nb x 256 partials, then the one-time 127-step
// prefix/suffix scan to form d_kernel, and the bias update.
__global__ __launch_bounds__(1024) void conv1d_train_reduce(
    const float* __restrict__ partial, int nb,
    const float* __restrict__ kern, const float* __restrict__ bias,
    float* __restrict__ out)
{
    const int tid   = threadIdx.x;
    const int col   = tid & 255;
    const int slice = tid >> 8;                 // 0..3
    const int chunk = (nb + 3) >> 2;
    const int lo    = slice * chunk;
    const int hi    = min(nb, lo + chunk);

    float a0 = 0.f, a1 = 0.f, a2 = 0.f, a3 = 0.f;
    float a4 = 0.f, a5 = 0.f, a6 = 0.f, a7 = 0.f;
    int i = lo;
    for (; i + 8 <= hi; i += 8) {
        a0 += partial[(size_t)(i + 0) * 256 + col];
        a1 += partial[(size_t)(i + 1) * 256 + col];
        a2 += partial[(size_t)(i + 2) * 256 + col];
        a3 += partial[(size_t)(i + 3) * 256 + col];
        a4 += partial[(size_t)(i + 4) * 256 + col];
        a5 += partial[(size_t)(i + 5) * 256 + col];
        a6 += partial[(size_t)(i + 6) * 256 + col];
        a7 += partial[(size_t)(i + 7) * 256 + col];
    }
    for (; i < hi; ++i) a0 += partial[(size_t)i * 256 + col];
    const float s = ((a0 + a1) + (a2 + a3)) + ((a4 + a5) + (a6 + a7));

    __shared__ float sl[4][256];
    __shared__ float colsum[256];
    sl[slice][col] = s;
    __syncthreads();
    if (tid < 256)
        colsum[tid] = (sl[0][tid] + sl[1][tid]) + (sl[2][tid] + sl[3][tid]);
    __syncthreads();

    if (tid < 128) {
        const float C0 = colsum[127];
        float pre = 0.f, suf = 0.f;
        for (int j = 0; j < 127; ++j) {
            const float g = colsum[j];           // broadcast
            const float h = colsum[128 + j];
            if (j < tid)  pre += g;
            if (j >= tid) suf += h;
        }
        const float dk = (C0 - pre - suf) * (1.f / (float)BATCH);
        out[tid] = kern[tid] - dk;
    }
    if (tid == 0) {
        const float db = colsum[255] * ((float)OUT_LEN / (float)BATCH);
        out[128] = bias[0] - db;
    }
}

extern "C" void kernel_launch(void* const* d_in, const int* in_sizes, int n_in,
                              void* d_out, int out_size, void* d_ws, size_t ws_size,
                              hipStream_t stream) {
    (void)in_sizes; (void)n_in; (void)out_size;
    const float* x    = (const float*)d_in[0];
    const float* y    = (const float*)d_in[1];
    const float* kern = (const float*)d_in[2];
    const float* bias = (const float*)d_in[3];
    float* out     = (float*)d_out;
    float* partial = (float*)d_ws;

    int nb = (int)(ws_size / (256 * sizeof(float)));
    if (nb > NB_MAX) nb = NB_MAX;
    if (nb < 1) nb = 1;

    hipLaunchKernelGGL(conv1d_train_main, dim3(nb), dim3(256), 0, stream,
                       x, y, kern, bias, partial, nb);
    hipLaunchKernelGGL(conv1d_train_reduce, dim3(1), dim3(1024), 0, stream,
                       partial, nb, kern, bias, out);
}

// Round 3
// 45.280 us; speedup vs baseline: 1.1201x; 1.1201x over previous
//
#include <hip/hip_runtime.h>
#include <math.h>

#define SEQ_LEN 4096
#define KSZ 128
#define OUT_LEN 3969
#define BATCH 8192
#define NB_MAX 1024

// One wave = one row. No barriers in the row loop.
// Per row: 16 independent float4 loads, pairwise sum, XOR-butterfly reduce
// (all lanes get identical totals), redundant sigmoid/dconv on all lanes,
// per-lane FMA into 4 edge-gradient accumulators held in registers.
// Head elems x[0..127] = lanes 0..31 of load 0; tail x[3968..4095] = lanes
// 32..63 of load 15. corr weight for j=127 is P[127]-ksum = 0 (interior).
// Partials written COLUMN-major: partial[col*nb + blk] so the column
// reduce reads contiguous memory.
__global__ __launch_bounds__(256, 4) void conv1d_train_main(
    const float* __restrict__ x, const float* __restrict__ y,
    const float* __restrict__ kern, const float* __restrict__ bias,
    float* __restrict__ partial, int nb)
{
    __shared__ float kk[KSZ];
    __shared__ float P[KSZ];      // inclusive prefix sums of kernel
    __shared__ float sl[4][256];  // per-wave partials for block combine

    const int tid  = threadIdx.x;
    const int wave = tid >> 6;
    const int lane = tid & 63;

    if (tid < KSZ) kk[tid] = kern[tid];
    __syncthreads();
    if (tid < KSZ) {
        float s = 0.f;
        for (int j = 0; j <= tid; ++j) s += kk[j];   // LDS broadcast reads
        P[tid] = s;
    }
    __syncthreads();
    const float ksum = P[KSZ - 1];
    const float bs   = bias[0];

    // Per-lane edge-correction weights.
    // head lane l<32: elems j=4l..4l+3, weight P[j]-ksum  (j=127 -> 0)
    // tail lane l>=32: elems 3968+4(l-32)+q, m=4(l-32)+q-1, weight -P[m]; m=-1 -> 0
    float w0, w1, w2, w3;
    if (lane < 32) {
        const int j = 4 * lane;
        w0 = P[j] - ksum; w1 = P[j + 1] - ksum;
        w2 = P[j + 2] - ksum; w3 = P[j + 3] - ksum;
    } else {
        const int m = 4 * (lane - 32) - 1;
        w0 = (m >= 0) ? -P[m] : 0.f;
        w1 = -P[m + 1]; w2 = -P[m + 2]; w3 = -P[m + 3];
    }

    float g0 = 0.f, g1 = 0.f, g2 = 0.f, g3 = 0.f;  // dconv-weighted edge accum
    float C0 = 0.f, db = 0.f;

    const int wg     = blockIdx.x * 4 + wave;
    const int stride = nb * 4;

    for (int b = wg; b < BATCH; b += stride) {
        const float4* xr = reinterpret_cast<const float4*>(x + (size_t)b * SEQ_LEN);
        float4 r[16];
#pragma unroll
        for (int i = 0; i < 16; ++i) r[i] = xr[i * 64 + lane];
        const float yv = y[b];                       // broadcast load

        float tot = 0.f;
#pragma unroll
        for (int i = 0; i < 16; ++i) tot += (r[i].x + r[i].y) + (r[i].z + r[i].w);

        const float4 e = (lane < 32) ? r[0] : r[15];
        float corr = ((w0 * e.x + w1 * e.y) + (w2 * e.z + w3 * e.w));

        float t = tot, c = corr;
#pragma unroll
        for (int off = 1; off < 64; off <<= 1) {
            t += __shfl_xor(t, off, 64);
            c += __shfl_xor(c, off, 64);
        }
        // all lanes now hold identical t, c
        const float logits = (ksum * t + c) * (1.f / (float)OUT_LEN) + bs;
        const float sig    = 1.f / (1.f + expf(-logits));
        const float dconv  = (sig - yv) * (1.f / (float)OUT_LEN);

        g0 += dconv * e.x; g1 += dconv * e.y;
        g2 += dconv * e.z; g3 += dconv * e.w;
        C0 += dconv * t;   db += dconv;
    }

    // Per-wave writeout to LDS: [0..126]=G, [127]=C0, [128..254]=H, [255]=db
    if (lane < 32) {
        const int j = 4 * lane;
        sl[wave][j]     = g0;
        sl[wave][j + 1] = g1;
        sl[wave][j + 2] = g2;
        if (j + 3 < 127) sl[wave][j + 3] = g3;   // skip unused G[127]
    } else {
        const int s0 = 4 * lane - 1;             // slot = 128 + m
        if (lane > 32) sl[wave][s0] = g0;        // lane 32 q=0 -> m=-1, skip
        sl[wave][s0 + 1] = g1;
        sl[wave][s0 + 2] = g2;
        sl[wave][s0 + 3] = g3;                   // lane 63 -> slot 254
    }
    if (lane == 0) { sl[wave][127] = C0; sl[wave][255] = db; }
    __syncthreads();
    if (tid < 256) {
        const float s = (sl[0][tid] + sl[1][tid]) + (sl[2][tid] + sl[3][tid]);
        partial[(size_t)tid * nb + blockIdx.x] = s;   // column-major
    }
}

// Stage 2: 256 blocks x 1 wave. Block c sums its contiguous column of nb
// floats -> colsum[c]. No LDS, no barriers.
__global__ __launch_bounds__(64) void conv1d_train_colreduce(
    const float* __restrict__ partial, int nb, float* __restrict__ colsum)
{
    const int c    = blockIdx.x;
    const int lane = threadIdx.x;
    const float* col = partial + (size_t)c * nb;

    float s = 0.f;
    for (int j = lane; j < nb; j += 64) s += col[j];   // coalesced
#pragma unroll
    for (int off = 1; off < 64; off <<= 1) s += __shfl_xor(s, off, 64);
    if (lane == 0) colsum[c] = s;
}

// Stage 3: one small block. 127-step prefix/suffix scan over the 256
// column sums, write kernel_new (128) + bias_new (1).
__global__ __launch_bounds__(256) void conv1d_train_finalize(
    const float* __restrict__ colsum_g,
    const float* __restrict__ kern, const float* __restrict__ bias,
    float* __restrict__ out)
{
    __shared__ float colsum[256];
    const int tid = threadIdx.x;
    colsum[tid] = colsum_g[tid];
    __syncthreads();

    if (tid < 128) {
        const float C0 = colsum[127];
        float pre = 0.f, suf = 0.f;
        for (int j = 0; j < 127; ++j) {
            const float g = colsum[j];           // broadcast
            const float h = colsum[128 + j];
            if (j < tid)  pre += g;
            if (j >= tid) suf += h;
        }
        const float dk = (C0 - pre - suf) * (1.f / (float)BATCH);
        out[tid] = kern[tid] - dk;
    }
    if (tid == 0) {
        const float db = colsum[255] * ((float)OUT_LEN / (float)BATCH);
        out[128] = bias[0] - db;
    }
}

extern "C" void kernel_launch(void* const* d_in, const int* in_sizes, int n_in,
                              void* d_out, int out_size, void* d_ws, size_t ws_size,
                              hipStream_t stream) {
    (void)in_sizes; (void)n_in; (void)out_size;
    const float* x    = (const float*)d_in[0];
    const float* y    = (const float*)d_in[1];
    const float* kern = (const float*)d_in[2];
    const float* bias = (const float*)d_in[3];
    float* out = (float*)d_out;

    // Workspace layout: partial[256 * nb] then colsum[256].
    int nb = NB_MAX;
    while (nb > 64 && (size_t)(256 * nb + 256) * sizeof(float) > ws_size) nb >>= 1;
    float* partial = (float*)d_ws;
    float* colsum  = partial + (size_t)256 * nb;

    hipLaunchKernelGGL(conv1d_train_main, dim3(nb), dim3(256), 0, stream,
                       x, y, kern, bias, partial, nb);
    hipLaunchKernelGGL(conv1d_train_colreduce, dim3(256), dim3(64), 0, stream,
                       partial, nb, colsum);
    hipLaunchKernelGGL(conv1d_train_finalize, dim3(1), dim3(256), 0, stream,
                       colsum, kern, bias, out);
}